// Round 3
// baseline (738.109 us; speedup 1.0000x reference)
//
#include <hip/hip_runtime.h>

#define D_FEAT 64
#define SUBN 128            // nodes per bin (LDS tile = 128*64*4 = 32 KB)
#define SUBN_SHIFT 7
#define CH 16384            // edges per binning chunk/block
#define NBINS_MAX 1024
#define SCAN_BLOCK 256
#define SCAN_ELEMS 1024

// ---------- fallback: direct atomic scatter-add (verified round 1) ----------
__global__ __launch_bounds__(256) void k_atomic_scatter(
    const float* __restrict__ x, const int* __restrict__ src,
    const int* __restrict__ tgt, float* __restrict__ out, int n_edges)
{
    const int lane = threadIdx.x & 63;
    const int wave = threadIdx.x >> 6;
    const int e = blockIdx.x * 4 + wave;
    if (e >= n_edges) return;
    const float v = x[(long long)src[e] * D_FEAT + lane];
    atomicAdd(&out[(long long)tgt[e] * D_FEAT + lane], v);
}

// ---------- pass A1: per-chunk histogram over bins (coalesced block-major write) ----------
__global__ __launch_bounds__(256) void k_bin_count(
    const int* __restrict__ tgt, int* __restrict__ cnt, int E, int NBINS)
{
    __shared__ int c[NBINS_MAX];
    const int tid = threadIdx.x;
    for (int i = tid; i < NBINS; i += 256) c[i] = 0;
    __syncthreads();
    const int base = blockIdx.x * CH;
    for (int i = tid; i < CH; i += 256) {
        int e = base + i;
        if (e < E) atomicAdd(&c[tgt[e] >> SUBN_SHIFT], 1);
    }
    __syncthreads();
    // block-major: cnt[chunk*NBINS + bin]  (fully coalesced full-line writes)
    for (int i = tid; i < NBINS; i += 256) cnt[(size_t)blockIdx.x * NBINS + i] = c[i];
}

// ---------- pass A2a: partial exclusive scan in BIN-MAJOR order, reading transposed ----------
__global__ __launch_bounds__(SCAN_BLOCK) void k_scan_partial_T(
    const int* __restrict__ cnt, int* __restrict__ off,
    int* __restrict__ bsum, int M, int NBINS, int NBLK)
{
    __shared__ int lds[SCAN_BLOCK];
    const int tid = threadIdx.x;
    const int base = blockIdx.x * SCAN_ELEMS + tid * 4;
    int v[4];
#pragma unroll
    for (int k = 0; k < 4; ++k) {
        int i = base + k;
        if (i < M) {
            int bin = i / NBLK;
            int blk = i - bin * NBLK;
            v[k] = cnt[(size_t)blk * NBINS + bin];   // transposed gather read
        } else v[k] = 0;
    }
    const int tsum = v[0] + v[1] + v[2] + v[3];
    int val = tsum;
    lds[tid] = val;
    __syncthreads();
    for (int d = 1; d < SCAN_BLOCK; d <<= 1) {
        int add = (tid >= d) ? lds[tid - d] : 0;
        __syncthreads();
        val += add;
        lds[tid] = val;
        __syncthreads();
    }
    if (tid == SCAN_BLOCK - 1) bsum[blockIdx.x] = val;   // inclusive block total
    int p = val - tsum;                                  // exclusive within block
#pragma unroll
    for (int k = 0; k < 4; ++k) {
        int i = base + k;
        if (i < M) { off[i] = p; p += v[k]; }
    }
}

// ---------- pass A2b: single-block exclusive scan of block sums (nb <= 1024) ----------
__global__ __launch_bounds__(1024) void k_scan_sums(int* __restrict__ bsum, int nb)
{
    __shared__ int lds[1024];
    const int tid = threadIdx.x;
    const int v = (tid < nb) ? bsum[tid] : 0;
    int val = v;
    lds[tid] = val;
    __syncthreads();
    for (int d = 1; d < 1024; d <<= 1) {
        int add = (tid >= d) ? lds[tid - d] : 0;
        __syncthreads();
        val += add;
        lds[tid] = val;
        __syncthreads();
    }
    if (tid < nb) bsum[tid] = val - v;                   // exclusive
}

// ---------- pass A2c: add block bases ----------
__global__ void k_scan_addp(int* __restrict__ off, const int* __restrict__ bsum, int M)
{
    int i = blockIdx.x * blockDim.x + threadIdx.x;
    if (i < M) off[i] += bsum[i / SCAN_ELEMS];
}

// ---------- pass A3: scatter edges into bin-grouped buffer (segment-local writes) ----------
__global__ __launch_bounds__(256) void k_bin_scatter(
    const int* __restrict__ src, const int* __restrict__ tgt,
    const int* __restrict__ off, int* __restrict__ binned,
    int E, int NBINS, int NBLK)
{
    __shared__ int ofs[NBINS_MAX];
    const int tid = threadIdx.x;
    const int b = blockIdx.x;
    for (int i = tid; i < NBINS; i += 256) ofs[i] = off[(size_t)i * NBLK + b];
    __syncthreads();
    const int base = b * CH;
    for (int i = tid; i < CH; i += 256) {
        int e = base + i;
        if (e < E) {
            int t = tgt[e];
            int s = src[e];
            int bin = t >> SUBN_SHIFT;
            int p = atomicAdd(&ofs[bin], 1);
            binned[p] = (s << SUBN_SHIFT) | (t & (SUBN - 1));   // pack src + local tgt
        }
    }
}

// ---------- pass B: one block per bin; accumulate 128x64 tile in LDS, write coalesced ----------
__global__ __launch_bounds__(256) void k_bin_gather(
    const float* __restrict__ x, const int* __restrict__ binned,
    const int* __restrict__ off, float* __restrict__ out,
    int N, int E, int NBLK, int NBINS)
{
    __shared__ float acc[SUBN * D_FEAT];                 // 32 KB
    const int tid = threadIdx.x;
    float4* a4 = (float4*)acc;
    for (int i = tid; i < SUBN * D_FEAT / 4; i += 256) a4[i] = make_float4(0.f, 0.f, 0.f, 0.f);
    __syncthreads();

    const int bin = blockIdx.x;
    const int start = off[(size_t)bin * NBLK];
    const int end = (bin + 1 < NBINS) ? off[(size_t)(bin + 1) * NBLK] : E;
    const int lane = tid & 63;
    const int w = tid >> 6;

    // 4 waves x 4-edge unroll: 4 outstanding random 256B x-row reads per wave
    for (int e0 = start + w * 4; e0 < end; e0 += 16) {
        int p0 = binned[e0];
        int p1 = (e0 + 1 < end) ? binned[e0 + 1] : -1;
        int p2 = (e0 + 2 < end) ? binned[e0 + 2] : -1;
        int p3 = (e0 + 3 < end) ? binned[e0 + 3] : -1;
        float v0 = x[(size_t)(p0 >> SUBN_SHIFT) * D_FEAT + lane];
        float v1 = (p1 >= 0) ? x[(size_t)(p1 >> SUBN_SHIFT) * D_FEAT + lane] : 0.f;
        float v2 = (p2 >= 0) ? x[(size_t)(p2 >> SUBN_SHIFT) * D_FEAT + lane] : 0.f;
        float v3 = (p3 >= 0) ? x[(size_t)(p3 >> SUBN_SHIFT) * D_FEAT + lane] : 0.f;
        atomicAdd(&acc[(p0 & (SUBN - 1)) * D_FEAT + lane], v0);
        if (p1 >= 0) atomicAdd(&acc[(p1 & (SUBN - 1)) * D_FEAT + lane], v1);
        if (p2 >= 0) atomicAdd(&acc[(p2 & (SUBN - 1)) * D_FEAT + lane], v2);
        if (p3 >= 0) atomicAdd(&acc[(p3 & (SUBN - 1)) * D_FEAT + lane], v3);
    }
    __syncthreads();

    const int binBase = bin * SUBN;
    const int nval = min(SUBN, N - binBase);
    float4* o4 = (float4*)(out + (size_t)binBase * D_FEAT);
    for (int i = tid; i < nval * (D_FEAT / 4); i += 256) o4[i] = a4[i];
}

extern "C" void kernel_launch(void* const* d_in, const int* in_sizes, int n_in,
                              void* d_out, int out_size, void* d_ws, size_t ws_size,
                              hipStream_t stream)
{
    const float* x  = (const float*)d_in[0];
    const int*   ei = (const int*)d_in[1];     // [2, E] flat int32
    const int E = in_sizes[1] / 2;
    const int N = out_size / D_FEAT;
    const int* src = ei;                        // edge_index[0] = source (gather)
    const int* tgt = ei + E;                    // edge_index[1] = target (scatter)
    float* out = (float*)d_out;

    const int NBINS = (N + SUBN - 1) / SUBN;                 // 782 for N=100K
    const int NBLK  = (E + CH - 1) / CH;                     // 98 for E=1.6M
    const long long M = (long long)NBINS * NBLK;             // 76,636
    const int nScan = (int)((M + SCAN_ELEMS - 1) / SCAN_ELEMS);
    // ws layout (int32): cnt[M] | off[M] | bsum[1024] | binned[E]
    const size_t need = ((size_t)2 * M + 1024 + (size_t)E) * sizeof(int);

    if (NBINS > NBINS_MAX || nScan > 1024 || ws_size < need ||
        (long long)N * SUBN >= (1LL << 31)) {
        // fallback: verified atomic path
        hipMemsetAsync(d_out, 0, (size_t)out_size * sizeof(float), stream);
        k_atomic_scatter<<<(E + 3) / 4, 256, 0, stream>>>(x, src, tgt, out, E);
        return;
    }

    int* cnt = (int*)d_ws;
    int* off = cnt + M;
    int* bsum = off + M;
    int* binned = bsum + 1024;

    k_bin_count<<<NBLK, 256, 0, stream>>>(tgt, cnt, E, NBINS);
    k_scan_partial_T<<<nScan, SCAN_BLOCK, 0, stream>>>(cnt, off, bsum, (int)M, NBINS, NBLK);
    k_scan_sums<<<1, 1024, 0, stream>>>(bsum, nScan);
    k_scan_addp<<<(int)((M + 255) / 256), 256, 0, stream>>>(off, bsum, (int)M);
    k_bin_scatter<<<NBLK, 256, 0, stream>>>(src, tgt, off, binned, E, NBINS, NBLK);
    k_bin_gather<<<NBINS, 256, 0, stream>>>(x, binned, off, out, N, E, NBLK, NBINS);
}

// Round 6
// 130.673 us; speedup vs baseline: 5.6485x; 5.6485x over previous
//
#include <hip/hip_runtime.h>

#define D_FEAT 64
#define SUBN 128            // nodes per bin
#define SUBN_SHIFT 7
#define CH 16384            // edges per binning chunk/block
#define NBINS_MAX 1024
#define SCAN_BLOCK 256
#define SCAN_ELEMS 1024

// ---------- fallback: direct atomic scatter-add (verified round 1) ----------
__global__ __launch_bounds__(256) void k_atomic_scatter(
    const float* __restrict__ x, const int* __restrict__ src,
    const int* __restrict__ tgt, float* __restrict__ out, int n_edges)
{
    const int lane = threadIdx.x & 63;
    const int wave = threadIdx.x >> 6;
    const int e = blockIdx.x * 4 + wave;
    if (e >= n_edges) return;
    const float v = x[(long long)src[e] * D_FEAT + lane];
    atomicAdd(&out[(long long)tgt[e] * D_FEAT + lane], v);
}

// ---------- pass A1: per-chunk histogram over bins ----------
__global__ __launch_bounds__(256) void k_bin_count(
    const int* __restrict__ tgt, int* __restrict__ cnt, int E, int NBINS)
{
    __shared__ int c[NBINS_MAX];
    const int tid = threadIdx.x;
    for (int i = tid; i < NBINS; i += 256) c[i] = 0;
    __syncthreads();
    const int base = blockIdx.x * CH;
    for (int i = tid; i < CH; i += 256) {
        int e = base + i;
        if (e < E) atomicAdd(&c[tgt[e] >> SUBN_SHIFT], 1);
    }
    __syncthreads();
    for (int i = tid; i < NBINS; i += 256) cnt[(size_t)blockIdx.x * NBINS + i] = c[i];
}

// ---------- pass A2a: partial exclusive scan in BIN-MAJOR order (transposed read) ----------
__global__ __launch_bounds__(SCAN_BLOCK) void k_scan_partial_T(
    const int* __restrict__ cnt, int* __restrict__ off,
    int* __restrict__ bsum, int M, int NBINS, int NBLK)
{
    __shared__ int lds[SCAN_BLOCK];
    const int tid = threadIdx.x;
    const int base = blockIdx.x * SCAN_ELEMS + tid * 4;
    int v[4];
#pragma unroll
    for (int k = 0; k < 4; ++k) {
        int i = base + k;
        if (i < M) {
            int bin = i / NBLK;
            int blk = i - bin * NBLK;
            v[k] = cnt[(size_t)blk * NBINS + bin];
        } else v[k] = 0;
    }
    const int tsum = v[0] + v[1] + v[2] + v[3];
    int val = tsum;
    lds[tid] = val;
    __syncthreads();
    for (int d = 1; d < SCAN_BLOCK; d <<= 1) {
        int add = (tid >= d) ? lds[tid - d] : 0;
        __syncthreads();
        val += add;
        lds[tid] = val;
        __syncthreads();
    }
    if (tid == SCAN_BLOCK - 1) bsum[blockIdx.x] = val;
    int p = val - tsum;
#pragma unroll
    for (int k = 0; k < 4; ++k) {
        int i = base + k;
        if (i < M) { off[i] = p; p += v[k]; }
    }
}

// ---------- pass A2b: single-block exclusive scan of block sums ----------
__global__ __launch_bounds__(1024) void k_scan_sums(int* __restrict__ bsum, int nb)
{
    __shared__ int lds[1024];
    const int tid = threadIdx.x;
    const int v = (tid < nb) ? bsum[tid] : 0;
    int val = v;
    lds[tid] = val;
    __syncthreads();
    for (int d = 1; d < 1024; d <<= 1) {
        int add = (tid >= d) ? lds[tid - d] : 0;
        __syncthreads();
        val += add;
        lds[tid] = val;
        __syncthreads();
    }
    if (tid < nb) bsum[tid] = val - v;
}

// ---------- pass A2c: add block bases ----------
__global__ void k_scan_addp(int* __restrict__ off, const int* __restrict__ bsum, int M)
{
    int i = blockIdx.x * blockDim.x + threadIdx.x;
    if (i < M) off[i] += bsum[i / SCAN_ELEMS];
}

// ---------- pass A3: scatter edges into bin-grouped buffer ----------
__global__ __launch_bounds__(256) void k_bin_scatter(
    const int* __restrict__ src, const int* __restrict__ tgt,
    const int* __restrict__ off, int* __restrict__ binned,
    int E, int NBINS, int NBLK)
{
    __shared__ int ofs[NBINS_MAX];
    const int tid = threadIdx.x;
    const int b = blockIdx.x;
    for (int i = tid; i < NBINS; i += 256) ofs[i] = off[(size_t)i * NBLK + b];
    __syncthreads();
    const int base = b * CH;
    for (int i = tid; i < CH; i += 256) {
        int e = base + i;
        if (e < E) {
            int t = tgt[e];
            int s = src[e];
            int bin = t >> SUBN_SHIFT;
            int p = atomicAdd(&ofs[bin], 1);
            binned[p] = (s << SUBN_SHIFT) | (t & (SUBN - 1));   // pack src + local tgt
        }
    }
}

// ---------- pass B: per-bin 128-bucket sort -> exact CSR (srcSorted, nodeOff) ----------
__global__ __launch_bounds__(256) void k_bin_sort(
    const int* __restrict__ binned, const int* __restrict__ off,
    int* __restrict__ srcSorted, int* __restrict__ nodeOff,
    int E, int N, int NBLK, int NBINS)
{
    __shared__ int hist[SUBN];
    __shared__ int ofs[SUBN];
    const int tid = threadIdx.x;
    const int bin = blockIdx.x;
    const int binStart = off[(size_t)bin * NBLK];
    const int binEnd = (bin + 1 < NBINS) ? off[(size_t)(bin + 1) * NBLK] : E;
    if (tid < SUBN) hist[tid] = 0;
    __syncthreads();
    for (int e = binStart + tid; e < binEnd; e += 256)
        atomicAdd(&hist[binned[e] & (SUBN - 1)], 1);
    __syncthreads();
    // exclusive scan of hist[128] (Hillis-Steele in LDS)
    int orig = (tid < SUBN) ? hist[tid] : 0;
    int val = orig;
    if (tid < SUBN) ofs[tid] = val;
    __syncthreads();
    for (int d = 1; d < SUBN; d <<= 1) {
        int add = (tid >= d && tid < SUBN) ? ofs[tid - d] : 0;
        __syncthreads();
        if (tid < SUBN) { val += add; ofs[tid] = val; }
        __syncthreads();
    }
    if (tid < SUBN) {
        int abs0 = binStart + (val - orig);    // absolute exclusive start
        ofs[tid] = abs0;
        int node = bin * SUBN + tid;
        if (node < N) nodeOff[node] = abs0;
    }
    if (bin == 0 && tid == 0) nodeOff[N] = E;
    __syncthreads();
    for (int e = binStart + tid; e < binEnd; e += 256) {
        int entry = binned[e];
        int p = atomicAdd(&ofs[entry & (SUBN - 1)], 1);
        srcSorted[p] = entry >> SUBN_SHIFT;    // writes confined to this bin's window
    }
}

// ---------- pass C: one wave per node, CSR gather, no atomics ----------
__global__ __launch_bounds__(256) void k_gather(
    const float* __restrict__ x, const int* __restrict__ srcSorted,
    const int* __restrict__ nodeOff, float* __restrict__ out, int N)
{
    const int lane = threadIdx.x & 63;
    const int wave = threadIdx.x >> 6;
    const int v = blockIdx.x * 4 + wave;
    if (v >= N) return;
    const int start = __builtin_amdgcn_readfirstlane(nodeOff[v]);
    const int end   = __builtin_amdgcn_readfirstlane(nodeOff[v + 1]);
    float acc = 0.f;
    int k = start;
    for (; k + 8 <= end; k += 8) {            // 8 outstanding 256B row reads
        int s0 = srcSorted[k + 0];
        int s1 = srcSorted[k + 1];
        int s2 = srcSorted[k + 2];
        int s3 = srcSorted[k + 3];
        int s4 = srcSorted[k + 4];
        int s5 = srcSorted[k + 5];
        int s6 = srcSorted[k + 6];
        int s7 = srcSorted[k + 7];
        float a0 = x[s0 * D_FEAT + lane];
        float a1 = x[s1 * D_FEAT + lane];
        float a2 = x[s2 * D_FEAT + lane];
        float a3 = x[s3 * D_FEAT + lane];
        float a4 = x[s4 * D_FEAT + lane];
        float a5 = x[s5 * D_FEAT + lane];
        float a6 = x[s6 * D_FEAT + lane];
        float a7 = x[s7 * D_FEAT + lane];
        acc += a0 + a1 + a2 + a3 + a4 + a5 + a6 + a7;
    }
    for (; k < end; ++k)
        acc += x[srcSorted[k] * D_FEAT + lane];
    out[(size_t)v * D_FEAT + lane] = acc;
}

extern "C" void kernel_launch(void* const* d_in, const int* in_sizes, int n_in,
                              void* d_out, int out_size, void* d_ws, size_t ws_size,
                              hipStream_t stream)
{
    const float* x  = (const float*)d_in[0];
    const int*   ei = (const int*)d_in[1];     // [2, E] flat int32
    const int E = in_sizes[1] / 2;
    const int N = out_size / D_FEAT;
    const int* src = ei;                        // edge_index[0] = source (gather)
    const int* tgt = ei + E;                    // edge_index[1] = target (scatter)
    float* out = (float*)d_out;

    const int NBINS = (N + SUBN - 1) / SUBN;                 // 782 for N=100K
    const int NBLK  = (E + CH - 1) / CH;                     // 98 for E=1.6M
    const long long M = (long long)NBINS * NBLK;             // 76,636
    const int nScan = (int)((M + SCAN_ELEMS - 1) / SCAN_ELEMS);
    // ws layout (int32): cnt[M] | off[M] | bsum[1024] | binned[E] | srcSorted[E] | nodeOff[N+1]
    const size_t need = ((size_t)2 * M + 1024 + 2 * (size_t)E + N + 1) * sizeof(int);

    if (NBINS > NBINS_MAX || nScan > 1024 || ws_size < need ||
        (long long)N * SUBN >= (1LL << 31)) {
        hipMemsetAsync(d_out, 0, (size_t)out_size * sizeof(float), stream);
        k_atomic_scatter<<<(E + 3) / 4, 256, 0, stream>>>(x, src, tgt, out, E);
        return;
    }

    int* cnt = (int*)d_ws;
    int* off = cnt + M;
    int* bsum = off + M;
    int* binned = bsum + 1024;
    int* srcSorted = binned + E;
    int* nodeOff = srcSorted + E;

    k_bin_count<<<NBLK, 256, 0, stream>>>(tgt, cnt, E, NBINS);
    k_scan_partial_T<<<nScan, SCAN_BLOCK, 0, stream>>>(cnt, off, bsum, (int)M, NBINS, NBLK);
    k_scan_sums<<<1, 1024, 0, stream>>>(bsum, nScan);
    k_scan_addp<<<(int)((M + 255) / 256), 256, 0, stream>>>(off, bsum, (int)M);
    k_bin_scatter<<<NBLK, 256, 0, stream>>>(src, tgt, off, binned, E, NBINS, NBLK);
    k_bin_sort<<<NBINS, 256, 0, stream>>>(binned, off, srcSorted, nodeOff, E, N, NBLK, NBINS);
    k_gather<<<(N + 3) / 4, 256, 0, stream>>>(x, srcSorted, nodeOff, out, N);
}

// Round 7
// 127.679 us; speedup vs baseline: 5.7810x; 1.0234x over previous
//
#include <hip/hip_runtime.h>

#define D_FEAT 64
#define SUBN 128            // nodes per bin
#define SUBN_SHIFT 7
#define CH 16384            // edges per binning chunk/block
#define NBINS_MAX 1024
#define SCAN_BLOCK 256
#define SCAN_ELEMS 1024
#define SCAN_SHIFT 10

// ---------- fallback: direct atomic scatter-add (verified round 1) ----------
__global__ __launch_bounds__(256) void k_atomic_scatter(
    const float* __restrict__ x, const int* __restrict__ src,
    const int* __restrict__ tgt, float* __restrict__ out, int n_edges)
{
    const int lane = threadIdx.x & 63;
    const int wave = threadIdx.x >> 6;
    const int e = blockIdx.x * 4 + wave;
    if (e >= n_edges) return;
    const float v = x[(long long)src[e] * D_FEAT + lane];
    atomicAdd(&out[(long long)tgt[e] * D_FEAT + lane], v);
}

// ---------- pass A1: per-chunk histogram over bins ----------
__global__ __launch_bounds__(256) void k_bin_count(
    const int* __restrict__ tgt, int* __restrict__ cnt, int E, int NBINS)
{
    __shared__ int c[NBINS_MAX];
    const int tid = threadIdx.x;
    for (int i = tid; i < NBINS; i += 256) c[i] = 0;
    __syncthreads();
    const int base = blockIdx.x * CH;
    for (int i = tid; i < CH; i += 256) {
        int e = base + i;
        if (e < E) atomicAdd(&c[tgt[e] >> SUBN_SHIFT], 1);
    }
    __syncthreads();
    for (int i = tid; i < NBINS; i += 256) cnt[(size_t)blockIdx.x * NBINS + i] = c[i];
}

// ---------- pass A2a: partial exclusive scan in BIN-MAJOR order (transposed read) ----------
__global__ __launch_bounds__(SCAN_BLOCK) void k_scan_partial_T(
    const int* __restrict__ cnt, int* __restrict__ off,
    int* __restrict__ bsum, int M, int NBINS, int NBLK)
{
    __shared__ int lds[SCAN_BLOCK];
    const int tid = threadIdx.x;
    const int base = blockIdx.x * SCAN_ELEMS + tid * 4;
    int v[4];
#pragma unroll
    for (int k = 0; k < 4; ++k) {
        int i = base + k;
        if (i < M) {
            int bin = i / NBLK;
            int blk = i - bin * NBLK;
            v[k] = cnt[(size_t)blk * NBINS + bin];
        } else v[k] = 0;
    }
    const int tsum = v[0] + v[1] + v[2] + v[3];
    int val = tsum;
    lds[tid] = val;
    __syncthreads();
    for (int d = 1; d < SCAN_BLOCK; d <<= 1) {
        int add = (tid >= d) ? lds[tid - d] : 0;
        __syncthreads();
        val += add;
        lds[tid] = val;
        __syncthreads();
    }
    if (tid == SCAN_BLOCK - 1) bsum[blockIdx.x] = val;
    int p = val - tsum;
#pragma unroll
    for (int k = 0; k < 4; ++k) {
        int i = base + k;
        if (i < M) { off[i] = p; p += v[k]; }
    }
}

// ---------- pass A2b: single-block exclusive scan of block sums ----------
__global__ __launch_bounds__(1024) void k_scan_sums(int* __restrict__ bsum, int nb)
{
    __shared__ int lds[1024];
    const int tid = threadIdx.x;
    const int v = (tid < nb) ? bsum[tid] : 0;
    int val = v;
    lds[tid] = val;
    __syncthreads();
    for (int d = 1; d < 1024; d <<= 1) {
        int add = (tid >= d) ? lds[tid - d] : 0;
        __syncthreads();
        val += add;
        lds[tid] = val;
        __syncthreads();
    }
    if (tid < nb) bsum[tid] = val - v;
}

// ---------- pass A3: scatter edges into bin-grouped buffer (bsum fixup fused) ----------
__global__ __launch_bounds__(256) void k_bin_scatter(
    const int* __restrict__ src, const int* __restrict__ tgt,
    const int* __restrict__ off, const int* __restrict__ bsum,
    int* __restrict__ binned, int E, int NBINS, int NBLK)
{
    __shared__ int ofs[NBINS_MAX];
    const int tid = threadIdx.x;
    const int b = blockIdx.x;
    for (int i = tid; i < NBINS; i += 256) {
        size_t idx = (size_t)i * NBLK + b;
        ofs[i] = off[idx] + bsum[idx >> SCAN_SHIFT];
    }
    __syncthreads();
    const int base = b * CH;
    for (int i = tid; i < CH; i += 256) {
        int e = base + i;
        if (e < E) {
            int t = tgt[e];
            int s = src[e];
            int bin = t >> SUBN_SHIFT;
            int p = atomicAdd(&ofs[bin], 1);
            binned[p] = (s << SUBN_SHIFT) | (t & (SUBN - 1));   // pack src + local tgt
        }
    }
}

// ---------- pass B: per-bin 128-bucket sort -> exact CSR (bsum fixup fused) ----------
__global__ __launch_bounds__(256) void k_bin_sort(
    const int* __restrict__ binned, const int* __restrict__ off,
    const int* __restrict__ bsum,
    int* __restrict__ srcSorted, int* __restrict__ nodeOff,
    int E, int N, int NBLK, int NBINS)
{
    __shared__ int hist[SUBN];
    __shared__ int ofs[SUBN];
    const int tid = threadIdx.x;
    const int bin = blockIdx.x;
    const size_t i0 = (size_t)bin * NBLK;
    const int binStart = off[i0] + bsum[i0 >> SCAN_SHIFT];
    int binEnd;
    if (bin + 1 < NBINS) {
        const size_t i1 = (size_t)(bin + 1) * NBLK;
        binEnd = off[i1] + bsum[i1 >> SCAN_SHIFT];
    } else binEnd = E;
    if (tid < SUBN) hist[tid] = 0;
    __syncthreads();
    for (int e = binStart + tid; e < binEnd; e += 256)
        atomicAdd(&hist[binned[e] & (SUBN - 1)], 1);
    __syncthreads();
    // exclusive scan of hist[128] (Hillis-Steele in LDS)
    int orig = (tid < SUBN) ? hist[tid] : 0;
    int val = orig;
    if (tid < SUBN) ofs[tid] = val;
    __syncthreads();
    for (int d = 1; d < SUBN; d <<= 1) {
        int add = (tid >= d && tid < SUBN) ? ofs[tid - d] : 0;
        __syncthreads();
        if (tid < SUBN) { val += add; ofs[tid] = val; }
        __syncthreads();
    }
    if (tid < SUBN) {
        int abs0 = binStart + (val - orig);    // absolute exclusive start
        ofs[tid] = abs0;
        int node = bin * SUBN + tid;
        if (node < N) nodeOff[node] = abs0;
    }
    if (bin == 0 && tid == 0) nodeOff[N] = E;
    __syncthreads();
    for (int e = binStart + tid; e < binEnd; e += 256) {
        int entry = binned[e];
        int p = atomicAdd(&ofs[entry & (SUBN - 1)], 1);
        srcSorted[p] = entry >> SUBN_SHIFT;    // writes confined to this bin's window
    }
}

// ---------- pass C: one wave per node, CSR gather, 16-deep MLP ----------
__global__ __launch_bounds__(256) void k_gather(
    const float* __restrict__ x, const int* __restrict__ srcSorted,
    const int* __restrict__ nodeOff, float* __restrict__ out, int N)
{
    const int lane = threadIdx.x & 63;
    const int wave = threadIdx.x >> 6;
    const int v = blockIdx.x * 4 + wave;
    if (v >= N) return;
    const int start = __builtin_amdgcn_readfirstlane(nodeOff[v]);
    const int end   = __builtin_amdgcn_readfirstlane(nodeOff[v + 1]);
    float acc = 0.f;
    int k = start;
    for (; k + 16 <= end; k += 16) {          // 16 outstanding 256B row reads
        int s[16];
#pragma unroll
        for (int j = 0; j < 16; ++j) s[j] = srcSorted[k + j];   // uniform -> s_load
        float a[16];
#pragma unroll
        for (int j = 0; j < 16; ++j) a[j] = x[(size_t)s[j] * D_FEAT + lane];
        float t0 = (a[0]+a[1])+(a[2]+a[3]), t1 = (a[4]+a[5])+(a[6]+a[7]);
        float t2 = (a[8]+a[9])+(a[10]+a[11]), t3 = (a[12]+a[13])+(a[14]+a[15]);
        acc += (t0 + t1) + (t2 + t3);
    }
    for (; k + 4 <= end; k += 4) {
        int s0 = srcSorted[k + 0];
        int s1 = srcSorted[k + 1];
        int s2 = srcSorted[k + 2];
        int s3 = srcSorted[k + 3];
        float a0 = x[(size_t)s0 * D_FEAT + lane];
        float a1 = x[(size_t)s1 * D_FEAT + lane];
        float a2 = x[(size_t)s2 * D_FEAT + lane];
        float a3 = x[(size_t)s3 * D_FEAT + lane];
        acc += (a0 + a1) + (a2 + a3);
    }
    for (; k < end; ++k)
        acc += x[(size_t)srcSorted[k] * D_FEAT + lane];
    out[(size_t)v * D_FEAT + lane] = acc;
}

extern "C" void kernel_launch(void* const* d_in, const int* in_sizes, int n_in,
                              void* d_out, int out_size, void* d_ws, size_t ws_size,
                              hipStream_t stream)
{
    const float* x  = (const float*)d_in[0];
    const int*   ei = (const int*)d_in[1];     // [2, E] flat int32
    const int E = in_sizes[1] / 2;
    const int N = out_size / D_FEAT;
    const int* src = ei;                        // edge_index[0] = source (gather)
    const int* tgt = ei + E;                    // edge_index[1] = target (scatter)
    float* out = (float*)d_out;

    const int NBINS = (N + SUBN - 1) / SUBN;                 // 782 for N=100K
    const int NBLK  = (E + CH - 1) / CH;                     // 98 for E=1.6M
    const long long M = (long long)NBINS * NBLK;             // 76,636
    const int nScan = (int)((M + SCAN_ELEMS - 1) / SCAN_ELEMS);
    // ws layout (int32): cnt[M] | off[M] | bsum[1024] | binned[E] | srcSorted[E] | nodeOff[N+1]
    const size_t need = ((size_t)2 * M + 1024 + 2 * (size_t)E + N + 1) * sizeof(int);

    if (NBINS > NBINS_MAX || nScan > 1024 || ws_size < need ||
        (long long)N * SUBN >= (1LL << 31)) {
        hipMemsetAsync(d_out, 0, (size_t)out_size * sizeof(float), stream);
        k_atomic_scatter<<<(E + 3) / 4, 256, 0, stream>>>(x, src, tgt, out, E);
        return;
    }

    int* cnt = (int*)d_ws;
    int* off = cnt + M;
    int* bsum = off + M;
    int* binned = bsum + 1024;
    int* srcSorted = binned + E;
    int* nodeOff = srcSorted + E;

    k_bin_count<<<NBLK, 256, 0, stream>>>(tgt, cnt, E, NBINS);
    k_scan_partial_T<<<nScan, SCAN_BLOCK, 0, stream>>>(cnt, off, bsum, (int)M, NBINS, NBLK);
    k_scan_sums<<<1, 1024, 0, stream>>>(bsum, nScan);
    k_bin_scatter<<<NBLK, 256, 0, stream>>>(src, tgt, off, bsum, binned, E, NBINS, NBLK);
    k_bin_sort<<<NBINS, 256, 0, stream>>>(binned, off, bsum, srcSorted, nodeOff, E, N, NBLK, NBINS);
    k_gather<<<(N + 3) / 4, 256, 0, stream>>>(x, srcSorted, nodeOff, out, N);
}

// Round 8
// 104.835 us; speedup vs baseline: 7.0406x; 1.2179x over previous
//
#include <hip/hip_runtime.h>

#define D_FEAT 64
#define SUBN 128            // nodes per bin
#define SUBN_SHIFT 7
#define NBINS_MAX 1024
#define SCAN_BLOCK 256
#define SCAN_ELEMS 1024
#define SCAN_SHIFT 10

// ---------- fallback: direct atomic scatter-add (verified round 1) ----------
__global__ __launch_bounds__(256) void k_atomic_scatter(
    const float* __restrict__ x, const int* __restrict__ src,
    const int* __restrict__ tgt, float* __restrict__ out, int n_edges)
{
    const int lane = threadIdx.x & 63;
    const int wave = threadIdx.x >> 6;
    const int e = blockIdx.x * 4 + wave;
    if (e >= n_edges) return;
    const float v = x[(long long)src[e] * D_FEAT + lane];
    atomicAdd(&out[(long long)tgt[e] * D_FEAT + lane], v);
}

// ---------- pass A1: per-chunk histogram over bins (CH runtime) ----------
__global__ __launch_bounds__(256) void k_bin_count(
    const int* __restrict__ tgt, int* __restrict__ cnt, int E, int NBINS, int CH)
{
    __shared__ int c[NBINS_MAX];
    const int tid = threadIdx.x;
    for (int i = tid; i < NBINS; i += 256) c[i] = 0;
    __syncthreads();
    const int base = blockIdx.x * CH;
    const int lim = min(E, base + CH);
    for (int e = base + tid; e < lim; e += 256)
        atomicAdd(&c[tgt[e] >> SUBN_SHIFT], 1);
    __syncthreads();
    for (int i = tid; i < NBINS; i += 256) cnt[(size_t)blockIdx.x * NBINS + i] = c[i];
}

// ---------- pass A2a: partial exclusive scan in BIN-MAJOR order (transposed read) ----------
__global__ __launch_bounds__(SCAN_BLOCK) void k_scan_partial_T(
    const int* __restrict__ cnt, int* __restrict__ off,
    int* __restrict__ bsum, int M, int NBINS, int NBLK)
{
    __shared__ int lds[SCAN_BLOCK];
    const int tid = threadIdx.x;
    const int base = blockIdx.x * SCAN_ELEMS + tid * 4;
    int v[4];
#pragma unroll
    for (int k = 0; k < 4; ++k) {
        int i = base + k;
        if (i < M) {
            int bin = i / NBLK;
            int blk = i - bin * NBLK;
            v[k] = cnt[(size_t)blk * NBINS + bin];
        } else v[k] = 0;
    }
    const int tsum = v[0] + v[1] + v[2] + v[3];
    int val = tsum;
    lds[tid] = val;
    __syncthreads();
    for (int d = 1; d < SCAN_BLOCK; d <<= 1) {
        int add = (tid >= d) ? lds[tid - d] : 0;
        __syncthreads();
        val += add;
        lds[tid] = val;
        __syncthreads();
    }
    if (tid == SCAN_BLOCK - 1) bsum[blockIdx.x] = val;
    int p = val - tsum;
#pragma unroll
    for (int k = 0; k < 4; ++k) {
        int i = base + k;
        if (i < M) { off[i] = p; p += v[k]; }
    }
}

// ---------- pass A2b: single-block exclusive scan of block sums ----------
__global__ __launch_bounds__(1024) void k_scan_sums(int* __restrict__ bsum, int nb)
{
    __shared__ int lds[1024];
    const int tid = threadIdx.x;
    const int v = (tid < nb) ? bsum[tid] : 0;
    int val = v;
    lds[tid] = val;
    __syncthreads();
    for (int d = 1; d < 1024; d <<= 1) {
        int add = (tid >= d) ? lds[tid - d] : 0;
        __syncthreads();
        val += add;
        lds[tid] = val;
        __syncthreads();
    }
    if (tid < nb) bsum[tid] = val - v;
}

// ---------- pass A3: scatter edges into bin-grouped buffer (bsum fixup fused) ----------
__global__ __launch_bounds__(256) void k_bin_scatter(
    const int* __restrict__ src, const int* __restrict__ tgt,
    const int* __restrict__ off, const int* __restrict__ bsum,
    int* __restrict__ binned, int E, int NBINS, int NBLK, int CH)
{
    __shared__ int ofs[NBINS_MAX];
    const int tid = threadIdx.x;
    const int b = blockIdx.x;
    for (int i = tid; i < NBINS; i += 256) {
        size_t idx = (size_t)i * NBLK + b;
        ofs[i] = off[idx] + bsum[idx >> SCAN_SHIFT];
    }
    __syncthreads();
    const int base = b * CH;
    const int lim = min(E, base + CH);
    for (int e = base + tid; e < lim; e += 256) {
        int t = tgt[e];
        int s = src[e];
        int bin = t >> SUBN_SHIFT;
        int p = atomicAdd(&ofs[bin], 1);
        binned[p] = (s << SUBN_SHIFT) | (t & (SUBN - 1));   // pack src + local tgt
    }
}

// ---------- pass B: per-bin 128-bucket sort -> exact CSR (bsum fixup fused) ----------
__global__ __launch_bounds__(256) void k_bin_sort(
    const int* __restrict__ binned, const int* __restrict__ off,
    const int* __restrict__ bsum,
    int* __restrict__ srcSorted, int* __restrict__ nodeOff,
    int E, int N, int NBLK, int NBINS)
{
    __shared__ int hist[SUBN];
    __shared__ int ofs[SUBN];
    const int tid = threadIdx.x;
    const int bin = blockIdx.x;
    const size_t i0 = (size_t)bin * NBLK;
    const int binStart = off[i0] + bsum[i0 >> SCAN_SHIFT];
    int binEnd;
    if (bin + 1 < NBINS) {
        const size_t i1 = (size_t)(bin + 1) * NBLK;
        binEnd = off[i1] + bsum[i1 >> SCAN_SHIFT];
    } else binEnd = E;
    if (tid < SUBN) hist[tid] = 0;
    __syncthreads();
    for (int e = binStart + tid; e < binEnd; e += 256)
        atomicAdd(&hist[binned[e] & (SUBN - 1)], 1);
    __syncthreads();
    // exclusive scan of hist[128] (Hillis-Steele in LDS)
    int orig = (tid < SUBN) ? hist[tid] : 0;
    int val = orig;
    if (tid < SUBN) ofs[tid] = val;
    __syncthreads();
    for (int d = 1; d < SUBN; d <<= 1) {
        int add = (tid >= d && tid < SUBN) ? ofs[tid - d] : 0;
        __syncthreads();
        if (tid < SUBN) { val += add; ofs[tid] = val; }
        __syncthreads();
    }
    if (tid < SUBN) {
        int abs0 = binStart + (val - orig);    // absolute exclusive start
        ofs[tid] = abs0;
        int node = bin * SUBN + tid;
        if (node < N) nodeOff[node] = abs0;
    }
    if (bin == 0 && tid == 0) nodeOff[N] = E;
    __syncthreads();
    for (int e = binStart + tid; e < binEnd; e += 256) {
        int entry = binned[e];
        int p = atomicAdd(&ofs[entry & (SUBN - 1)], 1);
        srcSorted[p] = entry >> SUBN_SHIFT;    // writes confined to this bin's window
    }
}

// ---------- pass C: one wave per node, CSR gather, 16-deep MLP ----------
__global__ __launch_bounds__(256) void k_gather(
    const float* __restrict__ x, const int* __restrict__ srcSorted,
    const int* __restrict__ nodeOff, float* __restrict__ out, int N)
{
    const int lane = threadIdx.x & 63;
    const int wave = threadIdx.x >> 6;
    const int v = blockIdx.x * 4 + wave;
    if (v >= N) return;
    const int start = __builtin_amdgcn_readfirstlane(nodeOff[v]);
    const int end   = __builtin_amdgcn_readfirstlane(nodeOff[v + 1]);
    float acc = 0.f;
    int k = start;
    for (; k + 16 <= end; k += 16) {
        int s[16];
#pragma unroll
        for (int j = 0; j < 16; ++j) s[j] = srcSorted[k + j];
        float a[16];
#pragma unroll
        for (int j = 0; j < 16; ++j) a[j] = x[(size_t)s[j] * D_FEAT + lane];
        float t0 = (a[0]+a[1])+(a[2]+a[3]), t1 = (a[4]+a[5])+(a[6]+a[7]);
        float t2 = (a[8]+a[9])+(a[10]+a[11]), t3 = (a[12]+a[13])+(a[14]+a[15]);
        acc += (t0 + t1) + (t2 + t3);
    }
    for (; k + 4 <= end; k += 4) {
        int s0 = srcSorted[k + 0];
        int s1 = srcSorted[k + 1];
        int s2 = srcSorted[k + 2];
        int s3 = srcSorted[k + 3];
        float a0 = x[(size_t)s0 * D_FEAT + lane];
        float a1 = x[(size_t)s1 * D_FEAT + lane];
        float a2 = x[(size_t)s2 * D_FEAT + lane];
        float a3 = x[(size_t)s3 * D_FEAT + lane];
        acc += (a0 + a1) + (a2 + a3);
    }
    for (; k < end; ++k)
        acc += x[(size_t)srcSorted[k] * D_FEAT + lane];
    out[(size_t)v * D_FEAT + lane] = acc;
}

static inline size_t ws_need(long long M, int E, int N) {
    return ((size_t)2 * M + 1024 + 2 * (size_t)E + N + 1) * sizeof(int);
}

extern "C" void kernel_launch(void* const* d_in, const int* in_sizes, int n_in,
                              void* d_out, int out_size, void* d_ws, size_t ws_size,
                              hipStream_t stream)
{
    const float* x  = (const float*)d_in[0];
    const int*   ei = (const int*)d_in[1];     // [2, E] flat int32
    const int E = in_sizes[1] / 2;
    const int N = out_size / D_FEAT;
    const int* src = ei;                        // edge_index[0] = source (gather)
    const int* tgt = ei + E;                    // edge_index[1] = target (scatter)
    float* out = (float*)d_out;

    const int NBINS = (N + SUBN - 1) / SUBN;                 // 782 for N=100K

    // pick the smallest chunk (most parallel prep) whose workspace fits
    int CH = 0, NBLK = 0; long long M = 0; int nScan = 0;
    const int ch_opts[3] = {4096, 8192, 16384};
    for (int c = 0; c < 3; ++c) {
        int ch = ch_opts[c];
        int nblk = (E + ch - 1) / ch;
        long long m = (long long)nblk * NBINS;
        int ns = (int)((m + SCAN_ELEMS - 1) / SCAN_ELEMS);
        if (ns <= 1024 && ws_need(m, E, N) <= ws_size) { CH = ch; NBLK = nblk; M = m; nScan = ns; break; }
    }

    if (CH == 0 || NBINS > NBINS_MAX || (long long)N * SUBN >= (1LL << 31)) {
        hipMemsetAsync(d_out, 0, (size_t)out_size * sizeof(float), stream);
        k_atomic_scatter<<<(E + 3) / 4, 256, 0, stream>>>(x, src, tgt, out, E);
        return;
    }

    int* cnt = (int*)d_ws;
    int* off = cnt + M;
    int* bsum = off + M;
    int* binned = bsum + 1024;
    int* srcSorted = binned + E;
    int* nodeOff = srcSorted + E;

    k_bin_count<<<NBLK, 256, 0, stream>>>(tgt, cnt, E, NBINS, CH);
    k_scan_partial_T<<<nScan, SCAN_BLOCK, 0, stream>>>(cnt, off, bsum, (int)M, NBINS, NBLK);
    k_scan_sums<<<1, 1024, 0, stream>>>(bsum, nScan);
    k_bin_scatter<<<NBLK, 256, 0, stream>>>(src, tgt, off, bsum, binned, E, NBINS, NBLK, CH);
    k_bin_sort<<<NBINS, 256, 0, stream>>>(binned, off, bsum, srcSorted, nodeOff, E, N, NBLK, NBINS);
    k_gather<<<(N + 3) / 4, 256, 0, stream>>>(x, srcSorted, nodeOff, out, N);
}